// Round 9
// baseline (596.286 us; speedup 1.0000x reference)
//
#include <hip/hip_runtime.h>
#include <hip/hip_bf16.h>
#include <cstdint>

// Problem constants
#define BB 4
#define SS 2048
#define DD 1024
#define HH 16
#define DKH 64

using bf16x8  = __attribute__((ext_vector_type(8))) __bf16;
using f32x4   = __attribute__((ext_vector_type(4))) float;
using ushort8 = __attribute__((ext_vector_type(8))) unsigned short;

__device__ __forceinline__ unsigned short f2bf(float f) {
  unsigned int u = __builtin_bit_cast(unsigned int, f);
  u += 0x7fffu + ((u >> 16) & 1u);   // round-to-nearest-even
  return (unsigned short)(u >> 16);
}

// global -> LDS direct copy, 16B per lane. LDS dest must be wave-uniform;
// HW writes lane i at ldsbase + i*16.
__device__ __forceinline__ void gload16(const void* g, void* l) {
  __builtin_amdgcn_global_load_lds(
      (const __attribute__((address_space(1))) void*)g,
      (__attribute__((address_space(3))) void*)l,
      16, 0, 0);
}

// ---------------- fp32 -> bf16 conversion ----------------
// one tensor per launch (activations: 4096 blocks; used serially vs GEMMs)
__global__ __launch_bounds__(256) void cvt_one(const float* __restrict__ s,
                                               unsigned short* __restrict__ d) {
  const int i = ((int)blockIdx.x * 256 + (int)threadIdx.x) * 8;
  const float4* p = reinterpret_cast<const float4*>(s + i);
  float4 x = p[0], y = p[1];
  ushort8 r;
  r[0] = f2bf(x.x); r[1] = f2bf(x.y); r[2] = f2bf(x.z); r[3] = f2bf(x.w);
  r[4] = f2bf(y.x); r[5] = f2bf(y.y); r[6] = f2bf(y.z); r[7] = f2bf(y.w);
  *reinterpret_cast<ushort8*>(d + i) = r;
}

// all 4 weight tensors in one launch: 4 segs x 512 blocks
struct CvtW {
  const float* src[4];
  unsigned short* dst[4];
};
__global__ __launch_bounds__(256) void cvt_w(CvtW a) {
  const int b = blockIdx.x, seg = b >> 9, boff = b & 511;
  const float* s = a.src[seg];
  unsigned short* d = a.dst[seg];
  const int i = (boff * 256 + (int)threadIdx.x) * 8;
  const float4* p = reinterpret_cast<const float4*>(s + i);
  float4 x = p[0], y = p[1];
  ushort8 r;
  r[0] = f2bf(x.x); r[1] = f2bf(x.y); r[2] = f2bf(x.z); r[3] = f2bf(x.w);
  r[4] = f2bf(y.x); r[5] = f2bf(y.y); r[6] = f2bf(y.z); r[7] = f2bf(y.w);
  *reinterpret_cast<ushort8*>(d + i) = r;
}

// ---------------- GEMM: C[M,N] = A[M,K] * Bt[N,K]^T + bias ----------------
// m97-structure: 128x128 tile, BK=32, 4 waves (2x2), 16x16x32 bf16 MFMA,
// global_load_lds width=16 staging, 2 barriers per K-step.
// Fixed shape: M=8192, N=1024, K=1024 -> 64 x 8 = 512 tiles, 1D grid with
// XCD-chunked swizzle (row-chunked: each XCD owns 8 row-panels x all col-
// panels; per-XCD L2 set = 2MB A-panel + 2MB B).
__global__ __launch_bounds__(256) void gemm_bt(const unsigned short* __restrict__ A,
                                               const unsigned short* __restrict__ Bt,
                                               const float* __restrict__ bias,
                                               void* __restrict__ Cout,
                                               int M, int N, int K, int out_f32) {
  __shared__ alignas(16) unsigned short As[128 * 32];
  __shared__ alignas(16) unsigned short Bs[128 * 32];
  const int lid = blockIdx.x;                 // 512 blocks
  const int swz = (lid & 7) * 64 + (lid >> 3);
  const int bx = swz >> 3, by = swz & 7;      // 64 row-tiles x 8 col-tiles
  const int tid = threadIdx.x;
  const int wid = tid >> 6, lane = tid & 63;
  const int lg = lane >> 4, li = lane & 15;
  const int row0 = bx * 128, col0 = by * 128;
  const int wr = (wid >> 1) * 64, wc = (wid & 1) * 64;

  f32x4 acc[4][4] = {};

  // staging: 512 chunks of 16B; thread t owns chunks {t, t+256}.
  // chunk c -> LDS byte c*16 -> tile row c>>2, k-offset (c&3)*8 elems.
  const int c1 = tid, c2 = tid + 256;
  const size_t aoff1 = (size_t)(row0 + (c1 >> 2)) * K + ((c1 & 3) * 8);
  const size_t aoff2 = (size_t)(row0 + (c2 >> 2)) * K + ((c2 & 3) * 8);
  const size_t boff1 = (size_t)(col0 + (c1 >> 2)) * K + ((c1 & 3) * 8);
  const size_t boff2 = (size_t)(col0 + (c2 >> 2)) * K + ((c2 & 3) * 8);
  char* asb = (char*)As; char* bsb = (char*)Bs;
  char* a_dst1 = asb + wid * 1024;
  char* a_dst2 = asb + 4096 + wid * 1024;
  char* b_dst1 = bsb + wid * 1024;
  char* b_dst2 = bsb + 4096 + wid * 1024;

  for (int k0 = 0; k0 < K; k0 += 32) {
    gload16(A + aoff1 + k0, a_dst1);
    gload16(A + aoff2 + k0, a_dst2);
    gload16(Bt + boff1 + k0, b_dst1);
    gload16(Bt + boff2 + k0, b_dst2);
    __syncthreads();   // compiler drains vmcnt before barrier -> tiles ready
    bf16x8 af[4], bfr[4];
#pragma unroll
    for (int i = 0; i < 4; i++) {
      af[i]  = *reinterpret_cast<const bf16x8*>(&As[(wr + i * 16 + li) * 32 + lg * 8]);
      bfr[i] = *reinterpret_cast<const bf16x8*>(&Bs[(wc + i * 16 + li) * 32 + lg * 8]);
    }
#pragma unroll
    for (int mi = 0; mi < 4; mi++)
#pragma unroll
      for (int ni = 0; ni < 4; ni++)
        acc[mi][ni] = __builtin_amdgcn_mfma_f32_16x16x32_bf16(af[mi], bfr[ni], acc[mi][ni], 0, 0, 0);
    __syncthreads();   // all reads done before next stage overwrites
  }

  // epilogue: C/D layout col = li, row = lg*4 + j  [m89-verified]
#pragma unroll
  for (int ni = 0; ni < 4; ni++) {
    const int col = col0 + wc + ni * 16 + li;
    const float bv = bias[col];
#pragma unroll
    for (int mi = 0; mi < 4; mi++) {
#pragma unroll
      for (int j = 0; j < 4; j++) {
        const int row = row0 + wr + mi * 16 + lg * 4 + j;
        const float val = acc[mi][ni][j] + bv;
        if (out_f32) ((float*)Cout)[(size_t)row * N + col] = val;
        else ((unsigned short*)Cout)[(size_t)row * N + col] = f2bf(val);
      }
    }
  }
}

// ---------------- flash attention ----------------
// One block = 4 waves = 64 Q-rows for one (b,h). KV tiles of 64.
// Wave w owns Q rows [q0+16w, q0+16w+16). Scores via mfma(Qfrag, Kfrag),
// online softmax per row (16-lane-group shuffles), PV via LDS round-trip of
// P and an LDS-transposed V tile (stride 72: V-read ~8 lanes/slot; revisit
// with SQ_LDS_BANK_CONFLICT evidence).
// 1D grid of 2048 with XCD-chunked swizzle: 8 heads per XCD -> K/V working
// set 4MB = one L2; kills the 8x cross-XCD K/V re-fetch.
__global__ __launch_bounds__(256) void attn(const unsigned short* __restrict__ Qp,
                                            const unsigned short* __restrict__ Kp,
                                            const unsigned short* __restrict__ Vp,
                                            unsigned short* __restrict__ Oc) {
  const int lid = blockIdx.x;                   // 2048 blocks
  const int swz = (lid & 7) * 256 + (lid >> 3);
  const int bh = swz >> 5;                      // 64 (b,h) pairs
  const int b = bh >> 4, h = bh & 15;
  const int q0 = (swz & 31) * 64;
  const int tid = threadIdx.x;
  const int wid = tid >> 6, lane = tid & 63;
  const int lg = lane >> 4, li = lane & 15;

  __shared__ alignas(16) unsigned short Vt[64][72];      // [dk][key], padded
  __shared__ alignas(16) unsigned short Pb[4][16][72];   // per-wave P tile, padded

  const size_t base = ((size_t)b * SS) * DD + h * DKH;
  const unsigned short* Qb = Qp + base;
  const unsigned short* Kb = Kp + base;
  const unsigned short* Vb = Vp + base;

  const int qrow = q0 + wid * 16 + li;
  const bf16x8 qf0 = *reinterpret_cast<const bf16x8*>(Qb + (size_t)qrow * DD + lg * 8);
  const bf16x8 qf1 = *reinterpret_cast<const bf16x8*>(Qb + (size_t)qrow * DD + 32 + lg * 8);

  f32x4 acc[4] = {};                                  // [dk-tile]: rows lg*4+j, col li
  float mrow[4] = {-1e30f, -1e30f, -1e30f, -1e30f};   // per row j (of group lg)
  float lrow[4] = {0.f, 0.f, 0.f, 0.f};

  const int vkey = tid & 63, vdk = (tid >> 6) * 16;   // V staging mapping

  for (int kv0 = 0; kv0 < SS; kv0 += 64) {
    // V tile -> regs (32B contiguous per thread)
    ushort8 v0 = *reinterpret_cast<const ushort8*>(Vb + (size_t)(kv0 + vkey) * DD + vdk);
    ushort8 v1 = *reinterpret_cast<const ushort8*>(Vb + (size_t)(kv0 + vkey) * DD + vdk + 8);

    // QK^T: K-frags straight from global (L2-resident per-XCD by swizzle)
    f32x4 sc[4];
#pragma unroll
    for (int n = 0; n < 4; n++) {
      bf16x8 kb0 = *reinterpret_cast<const bf16x8*>(Kb + (size_t)(kv0 + n * 16 + li) * DD + lg * 8);
      bf16x8 kb1 = *reinterpret_cast<const bf16x8*>(Kb + (size_t)(kv0 + n * 16 + li) * DD + 32 + lg * 8);
      f32x4 c = {};
      c = __builtin_amdgcn_mfma_f32_16x16x32_bf16(qf0, kb0, c, 0, 0, 0);
      c = __builtin_amdgcn_mfma_f32_16x16x32_bf16(qf1, kb1, c, 0, 0, 0);
      sc[n] = c;
    }

    // online softmax; row r = lg*4 + j, its 64 scores live across 16 lanes x 4 tiles
    float pvv[4][4]; float alpha[4];
#pragma unroll
    for (int j = 0; j < 4; j++) {
      float mx = fmaxf(fmaxf(sc[0][j], sc[1][j]), fmaxf(sc[2][j], sc[3][j]));
      mx = fmaxf(mx, __shfl_xor(mx, 1, 16));
      mx = fmaxf(mx, __shfl_xor(mx, 2, 16));
      mx = fmaxf(mx, __shfl_xor(mx, 4, 16));
      mx = fmaxf(mx, __shfl_xor(mx, 8, 16));
      mx *= 0.125f;                                   // 1/sqrt(DK)
      const float mnew = fmaxf(mrow[j], mx);
      alpha[j] = __expf(mrow[j] - mnew);
      float ps = 0.f;
#pragma unroll
      for (int n = 0; n < 4; n++) {
        const float p = __expf(sc[n][j] * 0.125f - mnew);
        pvv[n][j] = p; ps += p;
      }
      ps += __shfl_xor(ps, 1, 16);
      ps += __shfl_xor(ps, 2, 16);
      ps += __shfl_xor(ps, 4, 16);
      ps += __shfl_xor(ps, 8, 16);
      lrow[j] = lrow[j] * alpha[j] + ps;
      mrow[j] = mnew;
    }

    __syncthreads();   // previous iteration's LDS reads complete
#pragma unroll
    for (int i = 0; i < 8; i++) {          // transposed V store (conflict-light)
      Vt[vdk + i][vkey] = v0[i];
      Vt[vdk + 8 + i][vkey] = v1[i];
    }
#pragma unroll
    for (int n = 0; n < 4; n++)
#pragma unroll
      for (int j = 0; j < 4; j++)
        Pb[wid][lg * 4 + j][n * 16 + li] = f2bf(pvv[n][j]);
#pragma unroll
    for (int n = 0; n < 4; n++)            // rescale O accumulator
#pragma unroll
      for (int j = 0; j < 4; j++)
        acc[n][j] *= alpha[j];
    __syncthreads();   // Vt + P visible

    // PV: A-frag = P rows (m=li), B-frag = Vt rows (n=dk)
    const bf16x8 pf0 = *reinterpret_cast<const bf16x8*>(&Pb[wid][li][lg * 8]);
    const bf16x8 pf1 = *reinterpret_cast<const bf16x8*>(&Pb[wid][li][32 + lg * 8]);
#pragma unroll
    for (int n = 0; n < 4; n++) {
      bf16x8 vb0 = *reinterpret_cast<const bf16x8*>(&Vt[n * 16 + li][lg * 8]);
      bf16x8 vb1 = *reinterpret_cast<const bf16x8*>(&Vt[n * 16 + li][32 + lg * 8]);
      acc[n] = __builtin_amdgcn_mfma_f32_16x16x32_bf16(pf0, vb0, acc[n], 0, 0, 0);
      acc[n] = __builtin_amdgcn_mfma_f32_16x16x32_bf16(pf1, vb1, acc[n], 0, 0, 0);
    }
  }

  // normalize + store concat (bf16)
  float inv[4];
#pragma unroll
  for (int j = 0; j < 4; j++) inv[j] = 1.0f / lrow[j];
  unsigned short* Ob = Oc + base;
#pragma unroll
  for (int n = 0; n < 4; n++)
#pragma unroll
    for (int j = 0; j < 4; j++) {
      const int r = q0 + wid * 16 + lg * 4 + j;
      Ob[(size_t)r * DD + n * 16 + li] = f2bf(acc[n][j] * inv[j]);
    }
}

// ---------------- launch ----------------
extern "C" void kernel_launch(void* const* d_in, const int* in_sizes, int n_in,
                              void* d_out, int out_size, void* d_ws, size_t ws_size,
                              hipStream_t stream) {
  const float* q  = (const float*)d_in[0];
  const float* k  = (const float*)d_in[1];
  const float* v  = (const float*)d_in[2];
  const float* Wq = (const float*)d_in[3];
  const float* bq = (const float*)d_in[4];
  const float* Wk = (const float*)d_in[5];
  const float* bk = (const float*)d_in[6];
  const float* Wv = (const float*)d_in[7];
  const float* bv = (const float*)d_in[8];
  const float* Wo = (const float*)d_in[9];
  const float* bo = (const float*)d_in[10];
  float* out = (float*)d_out;

  const size_t NE = (size_t)BB * SS * DD;  // 8,388,608
  const size_t WE = (size_t)DD * DD;       // 1,048,576
  // ws layout (ushort elems): ab (staging, reused q->k->v, then attn out) |
  // Qp | Kp | Vp | Wqb Wkb Wvb Wob.  Total = 4*NE + 4*WE elems = 72 MiB.
  unsigned short* ws  = (unsigned short*)d_ws;
  unsigned short* ab  = ws;                // activation staging / attn concat
  unsigned short* Qp  = ab + NE;
  unsigned short* Kp  = Qp + NE;
  unsigned short* Vp  = Kp + NE;
  unsigned short* Wqb = Vp + NE;
  unsigned short* Wkb = Wqb + WE;
  unsigned short* Wvb = Wkb + WE;
  unsigned short* Wob = Wvb + WE;
  (void)ws_size; (void)in_sizes; (void)n_in; (void)out_size;

  CvtW cw;
  cw.src[0] = Wq; cw.dst[0] = Wqb;
  cw.src[1] = Wk; cw.dst[1] = Wkb;
  cw.src[2] = Wv; cw.dst[2] = Wvb;
  cw.src[3] = Wo; cw.dst[3] = Wob;
  cvt_w<<<2048, 256, 0, stream>>>(cw);

  // serialized cvt->GEMM through one staging buffer (stream order guards ab)
  cvt_one<<<4096, 256, 0, stream>>>(q, ab);
  gemm_bt<<<512, 256, 0, stream>>>(ab, Wqb, bq, Qp, 8192, 1024, 1024, 0);
  cvt_one<<<4096, 256, 0, stream>>>(k, ab);
  gemm_bt<<<512, 256, 0, stream>>>(ab, Wkb, bk, Kp, 8192, 1024, 1024, 0);
  cvt_one<<<4096, 256, 0, stream>>>(v, ab);
  gemm_bt<<<512, 256, 0, stream>>>(ab, Wvb, bv, Vp, 8192, 1024, 1024, 0);

  attn<<<2048, 256, 0, stream>>>(Qp, Kp, Vp, ab);   // ab dead -> attn concat

  gemm_bt<<<512, 256, 0, stream>>>(ab, Wob, bo, out, 8192, 1024, 1024, 1);
}

// Round 10
// 522.766 us; speedup vs baseline: 1.1406x; 1.1406x over previous
//
#include <hip/hip_runtime.h>
#include <hip/hip_bf16.h>
#include <cstdint>

// Problem constants
#define BB 4
#define SS 2048
#define DD 1024
#define HH 16
#define DKH 64

using bf16x8  = __attribute__((ext_vector_type(8))) __bf16;
using f32x4   = __attribute__((ext_vector_type(4))) float;
using ushort8 = __attribute__((ext_vector_type(8))) unsigned short;

__device__ __forceinline__ unsigned short f2bf(float f) {
  unsigned int u = __builtin_bit_cast(unsigned int, f);
  u += 0x7fffu + ((u >> 16) & 1u);   // round-to-nearest-even
  return (unsigned short)(u >> 16);
}

// global -> LDS direct copy, 16B per lane. LDS dest must be wave-uniform;
// HW writes lane i at ldsbase + i*16.
__device__ __forceinline__ void gload16(const void* g, void* l) {
  __builtin_amdgcn_global_load_lds(
      (const __attribute__((address_space(1))) void*)g,
      (__attribute__((address_space(3))) void*)l,
      16, 0, 0);
}

// ---------------- fp32 -> bf16 conversion ----------------
__global__ __launch_bounds__(256) void cvt_one(const float* __restrict__ s,
                                               unsigned short* __restrict__ d) {
  const int i = ((int)blockIdx.x * 256 + (int)threadIdx.x) * 8;
  const float4* p = reinterpret_cast<const float4*>(s + i);
  float4 x = p[0], y = p[1];
  ushort8 r;
  r[0] = f2bf(x.x); r[1] = f2bf(x.y); r[2] = f2bf(x.z); r[3] = f2bf(x.w);
  r[4] = f2bf(y.x); r[5] = f2bf(y.y); r[6] = f2bf(y.z); r[7] = f2bf(y.w);
  *reinterpret_cast<ushort8*>(d + i) = r;
}

struct CvtW {
  const float* src[4];
  unsigned short* dst[4];
};
__global__ __launch_bounds__(256) void cvt_w(CvtW a) {
  const int b = blockIdx.x, seg = b >> 9, boff = b & 511;
  const float* s = a.src[seg];
  unsigned short* d = a.dst[seg];
  const int i = (boff * 256 + (int)threadIdx.x) * 8;
  const float4* p = reinterpret_cast<const float4*>(s + i);
  float4 x = p[0], y = p[1];
  ushort8 r;
  r[0] = f2bf(x.x); r[1] = f2bf(x.y); r[2] = f2bf(x.z); r[3] = f2bf(x.w);
  r[4] = f2bf(y.x); r[5] = f2bf(y.y); r[6] = f2bf(y.z); r[7] = f2bf(y.w);
  *reinterpret_cast<ushort8*>(d + i) = r;
}

// ---------------- GEMM: unchanged m97-structure (known-good) ----------------
__global__ __launch_bounds__(256) void gemm_bt(const unsigned short* __restrict__ A,
                                               const unsigned short* __restrict__ Bt,
                                               const float* __restrict__ bias,
                                               void* __restrict__ Cout,
                                               int M, int N, int K, int out_f32) {
  __shared__ alignas(16) unsigned short As[128 * 32];
  __shared__ alignas(16) unsigned short Bs[128 * 32];
  const int lid = blockIdx.x;                 // 512 blocks
  const int swz = (lid & 7) * 64 + (lid >> 3);
  const int bx = swz >> 3, by = swz & 7;      // 64 row-tiles x 8 col-tiles
  const int tid = threadIdx.x;
  const int wid = tid >> 6, lane = tid & 63;
  const int lg = lane >> 4, li = lane & 15;
  const int row0 = bx * 128, col0 = by * 128;
  const int wr = (wid >> 1) * 64, wc = (wid & 1) * 64;

  f32x4 acc[4][4] = {};

  const int c1 = tid, c2 = tid + 256;
  const size_t aoff1 = (size_t)(row0 + (c1 >> 2)) * K + ((c1 & 3) * 8);
  const size_t aoff2 = (size_t)(row0 + (c2 >> 2)) * K + ((c2 & 3) * 8);
  const size_t boff1 = (size_t)(col0 + (c1 >> 2)) * K + ((c1 & 3) * 8);
  const size_t boff2 = (size_t)(col0 + (c2 >> 2)) * K + ((c2 & 3) * 8);
  char* asb = (char*)As; char* bsb = (char*)Bs;
  char* a_dst1 = asb + wid * 1024;
  char* a_dst2 = asb + 4096 + wid * 1024;
  char* b_dst1 = bsb + wid * 1024;
  char* b_dst2 = bsb + 4096 + wid * 1024;

  for (int k0 = 0; k0 < K; k0 += 32) {
    gload16(A + aoff1 + k0, a_dst1);
    gload16(A + aoff2 + k0, a_dst2);
    gload16(Bt + boff1 + k0, b_dst1);
    gload16(Bt + boff2 + k0, b_dst2);
    __syncthreads();
    bf16x8 af[4], bfr[4];
#pragma unroll
    for (int i = 0; i < 4; i++) {
      af[i]  = *reinterpret_cast<const bf16x8*>(&As[(wr + i * 16 + li) * 32 + lg * 8]);
      bfr[i] = *reinterpret_cast<const bf16x8*>(&Bs[(wc + i * 16 + li) * 32 + lg * 8]);
    }
#pragma unroll
    for (int mi = 0; mi < 4; mi++)
#pragma unroll
      for (int ni = 0; ni < 4; ni++)
        acc[mi][ni] = __builtin_amdgcn_mfma_f32_16x16x32_bf16(af[mi], bfr[ni], acc[mi][ni], 0, 0, 0);
    __syncthreads();
  }

#pragma unroll
  for (int ni = 0; ni < 4; ni++) {
    const int col = col0 + wc + ni * 16 + li;
    const float bv = bias[col];
#pragma unroll
    for (int mi = 0; mi < 4; mi++) {
#pragma unroll
      for (int j = 0; j < 4; j++) {
        const int row = row0 + wr + mi * 16 + lg * 4 + j;
        const float val = acc[mi][ni][j] + bv;
        if (out_f32) ((float*)Cout)[(size_t)row * N + col] = val;
        else ((unsigned short*)Cout)[(size_t)row * N + col] = f2bf(val);
      }
    }
  }
}

// ---------------- flash attention ----------------
// R9 counters: MfmaUtil 8.5 / VALUBusy 38 / Occ 42 -> latency-bound on 4x-
// redundant scattered global K reads. Fix: K tile (64x64) staged once per
// block via global_load_lds (coalesced), double-buffered, XOR-swizzled via
// pre-swizzled SOURCE + swizzled ds_read (linear LDS dest; rule #21).
// Softmax / PV / layouts unchanged from the validated R9 kernel.
__global__ __launch_bounds__(256) void attn(const unsigned short* __restrict__ Qp,
                                            const unsigned short* __restrict__ Kp,
                                            const unsigned short* __restrict__ Vp,
                                            unsigned short* __restrict__ Oc) {
  const int lid = blockIdx.x;                   // 2048 blocks
  const int swz = (lid & 7) * 256 + (lid >> 3);
  const int bh = swz >> 5;                      // 64 (b,h) pairs
  const int b = bh >> 4, h = bh & 15;
  const int q0 = (swz & 31) * 64;
  const int tid = threadIdx.x;
  const int wid = tid >> 6, lane = tid & 63;
  const int lg = lane >> 4, li = lane & 15;

  __shared__ alignas(16) unsigned short Ks[2][64 * 64];  // K dbuf, 8KB each
  __shared__ alignas(16) unsigned short Vt[64][72];      // [dk][key], padded
  __shared__ alignas(16) unsigned short Pb[4][16][72];   // per-wave P tile

  const size_t base = ((size_t)b * SS) * DD + h * DKH;
  const unsigned short* Qb = Qp + base;
  const unsigned short* Kb = Kp + base;
  const unsigned short* Vb = Vp + base;

  const int qrow = q0 + wid * 16 + li;
  const bf16x8 qf0 = *reinterpret_cast<const bf16x8*>(Qb + (size_t)qrow * DD + lg * 8);
  const bf16x8 qf1 = *reinterpret_cast<const bf16x8*>(Qb + (size_t)qrow * DD + 32 + lg * 8);

  f32x4 acc[4] = {};                                  // rows lg*4+j, col li
  float mrow[4] = {-1e30f, -1e30f, -1e30f, -1e30f};
  float lrow[4] = {0.f, 0.f, 0.f, 0.f};

  const int vkey = tid & 63, vdk = (tid >> 6) * 16;   // V staging mapping

  // K staging precompute: 512 chunks of 16B; thread t owns {t, t+256}.
  // chunk c -> LDS byte c*16 (linear) -> row c>>3, slot c&7. Source is
  // pre-swizzled: slot s holds global chunk s ^ (row&7)  (involution).
  const int c0 = tid, c1 = tid + 256;
  const int r0c = c0 >> 3, r1c = c1 >> 3;
  const size_t koff0 = (size_t)r0c * DD + (((c0 & 7) ^ (r0c & 7)) * 8);
  const size_t koff1 = (size_t)r1c * DD + (((c1 & 7) ^ (r1c & 7)) * 8);
  char* ksb = (char*)Ks;
  // wave-uniform LDS dests (lane*16 added by HW)
  char* kdst0 = ksb + wid * 1024;          // + buf*8192 (+0)
  char* kdst1 = ksb + 4096 + wid * 1024;   // + buf*8192

  // prologue: stage tile 0 into buf 0
  gload16(Kb + koff0, kdst0);
  gload16(Kb + koff1, kdst1);
  __syncthreads();
  int buf = 0;

  const int swk = li & 7;                  // read-side swizzle key (row&7)

  for (int kv0 = 0; kv0 < SS; kv0 += 64) {
    // prefetch next K tile into buf^1 (its previous readers passed barrier2)
    if (kv0 + 64 < SS) {
      const int nb = buf ^ 1;
      gload16(Kb + (size_t)(kv0 + 64) * DD + koff0, kdst0 + nb * 8192);
      gload16(Kb + (size_t)(kv0 + 64) * DD + koff1, kdst1 + nb * 8192);
    }

    // V tile -> regs (32B contiguous per thread)
    ushort8 v0 = *reinterpret_cast<const ushort8*>(Vb + (size_t)(kv0 + vkey) * DD + vdk);
    ushort8 v1 = *reinterpret_cast<const ushort8*>(Vb + (size_t)(kv0 + vkey) * DD + vdk + 8);

    // QK^T from LDS (swizzled reads: 2 lanes/slot = conflict-free)
    f32x4 sc[4];
#pragma unroll
    for (int n = 0; n < 4; n++) {
      const unsigned short* krow = &Ks[buf][(n * 16 + li) * 64];
      bf16x8 kb0 = *reinterpret_cast<const bf16x8*>(&krow[(lg ^ swk) * 8]);
      bf16x8 kb1 = *reinterpret_cast<const bf16x8*>(&krow[((lg + 4) ^ swk) * 8]);
      f32x4 c = {};
      c = __builtin_amdgcn_mfma_f32_16x16x32_bf16(qf0, kb0, c, 0, 0, 0);
      c = __builtin_amdgcn_mfma_f32_16x16x32_bf16(qf1, kb1, c, 0, 0, 0);
      sc[n] = c;
    }

    // online softmax; row r = lg*4 + j across 16 lanes x 4 tiles
    float pvv[4][4]; float alpha[4];
#pragma unroll
    for (int j = 0; j < 4; j++) {
      float mx = fmaxf(fmaxf(sc[0][j], sc[1][j]), fmaxf(sc[2][j], sc[3][j]));
      mx = fmaxf(mx, __shfl_xor(mx, 1, 16));
      mx = fmaxf(mx, __shfl_xor(mx, 2, 16));
      mx = fmaxf(mx, __shfl_xor(mx, 4, 16));
      mx = fmaxf(mx, __shfl_xor(mx, 8, 16));
      mx *= 0.125f;                                   // 1/sqrt(DK)
      const float mnew = fmaxf(mrow[j], mx);
      alpha[j] = __expf(mrow[j] - mnew);
      float ps = 0.f;
#pragma unroll
      for (int n = 0; n < 4; n++) {
        const float p = __expf(sc[n][j] * 0.125f - mnew);
        pvv[n][j] = p; ps += p;
      }
      ps += __shfl_xor(ps, 1, 16);
      ps += __shfl_xor(ps, 2, 16);
      ps += __shfl_xor(ps, 4, 16);
      ps += __shfl_xor(ps, 8, 16);
      lrow[j] = lrow[j] * alpha[j] + ps;
      mrow[j] = mnew;
    }

    __syncthreads();   // prev-iter Vt/Pb reads done; drains K-stage + V loads
#pragma unroll
    for (int i = 0; i < 8; i++) {          // transposed V store
      Vt[vdk + i][vkey] = v0[i];
      Vt[vdk + 8 + i][vkey] = v1[i];
    }
#pragma unroll
    for (int n = 0; n < 4; n++)
#pragma unroll
      for (int j = 0; j < 4; j++)
        Pb[wid][lg * 4 + j][n * 16 + li] = f2bf(pvv[n][j]);
#pragma unroll
    for (int n = 0; n < 4; n++)            // rescale O accumulator
#pragma unroll
      for (int j = 0; j < 4; j++)
        acc[n][j] *= alpha[j];
    __syncthreads();   // Vt + P visible

    // PV: A-frag = P rows (m=li), B-frag = Vt rows (n=dk)
    const bf16x8 pf0 = *reinterpret_cast<const bf16x8*>(&Pb[wid][li][lg * 8]);
    const bf16x8 pf1 = *reinterpret_cast<const bf16x8*>(&Pb[wid][li][32 + lg * 8]);
#pragma unroll
    for (int n = 0; n < 4; n++) {
      bf16x8 vb0 = *reinterpret_cast<const bf16x8*>(&Vt[n * 16 + li][lg * 8]);
      bf16x8 vb1 = *reinterpret_cast<const bf16x8*>(&Vt[n * 16 + li][32 + lg * 8]);
      acc[n] = __builtin_amdgcn_mfma_f32_16x16x32_bf16(pf0, vb0, acc[n], 0, 0, 0);
      acc[n] = __builtin_amdgcn_mfma_f32_16x16x32_bf16(pf1, vb1, acc[n], 0, 0, 0);
    }
    buf ^= 1;
  }

  // normalize + store concat (bf16)
  float inv[4];
#pragma unroll
  for (int j = 0; j < 4; j++) inv[j] = 1.0f / lrow[j];
  unsigned short* Ob = Oc + base;
#pragma unroll
  for (int n = 0; n < 4; n++)
#pragma unroll
    for (int j = 0; j < 4; j++) {
      const int r = q0 + wid * 16 + lg * 4 + j;
      Ob[(size_t)r * DD + n * 16 + li] = f2bf(acc[n][j] * inv[j]);
    }
}

// ---------------- launch ----------------
extern "C" void kernel_launch(void* const* d_in, const int* in_sizes, int n_in,
                              void* d_out, int out_size, void* d_ws, size_t ws_size,
                              hipStream_t stream) {
  const float* q  = (const float*)d_in[0];
  const float* k  = (const float*)d_in[1];
  const float* v  = (const float*)d_in[2];
  const float* Wq = (const float*)d_in[3];
  const float* bq = (const float*)d_in[4];
  const float* Wk = (const float*)d_in[5];
  const float* bk = (const float*)d_in[6];
  const float* Wv = (const float*)d_in[7];
  const float* bv = (const float*)d_in[8];
  const float* Wo = (const float*)d_in[9];
  const float* bo = (const float*)d_in[10];
  float* out = (float*)d_out;

  const size_t NE = (size_t)BB * SS * DD;  // 8,388,608
  const size_t WE = (size_t)DD * DD;       // 1,048,576
  unsigned short* ws  = (unsigned short*)d_ws;
  unsigned short* ab  = ws;                // activation staging / attn concat
  unsigned short* Qp  = ab + NE;
  unsigned short* Kp  = Qp + NE;
  unsigned short* Vp  = Kp + NE;
  unsigned short* Wqb = Vp + NE;
  unsigned short* Wkb = Wqb + WE;
  unsigned short* Wvb = Wkb + WE;
  unsigned short* Wob = Wvb + WE;
  (void)ws_size; (void)in_sizes; (void)n_in; (void)out_size;

  CvtW cw;
  cw.src[0] = Wq; cw.dst[0] = Wqb;
  cw.src[1] = Wk; cw.dst[1] = Wkb;
  cw.src[2] = Wv; cw.dst[2] = Wvb;
  cw.src[3] = Wo; cw.dst[3] = Wob;
  cvt_w<<<2048, 256, 0, stream>>>(cw);

  cvt_one<<<4096, 256, 0, stream>>>(q, ab);
  gemm_bt<<<512, 256, 0, stream>>>(ab, Wqb, bq, Qp, 8192, 1024, 1024, 0);
  cvt_one<<<4096, 256, 0, stream>>>(k, ab);
  gemm_bt<<<512, 256, 0, stream>>>(ab, Wkb, bk, Kp, 8192, 1024, 1024, 0);
  cvt_one<<<4096, 256, 0, stream>>>(v, ab);
  gemm_bt<<<512, 256, 0, stream>>>(ab, Wvb, bv, Vp, 8192, 1024, 1024, 0);

  attn<<<2048, 256, 0, stream>>>(Qp, Kp, Vp, ab);   // ab dead -> attn concat

  gemm_bt<<<512, 256, 0, stream>>>(ab, Wob, bo, out, 8192, 1024, 1024, 1);
}

// Round 11
// 501.186 us; speedup vs baseline: 1.1897x; 1.0431x over previous
//
#include <hip/hip_runtime.h>
#include <hip/hip_bf16.h>
#include <cstdint>

// Problem constants
#define BB 4
#define SS 2048
#define DD 1024
#define HH 16
#define DKH 64

using bf16x8  = __attribute__((ext_vector_type(8))) __bf16;
using f32x4   = __attribute__((ext_vector_type(4))) float;
using ushort8 = __attribute__((ext_vector_type(8))) unsigned short;

__device__ __forceinline__ unsigned short f2bf(float f) {
  unsigned int u = __builtin_bit_cast(unsigned int, f);
  u += 0x7fffu + ((u >> 16) & 1u);   // round-to-nearest-even
  return (unsigned short)(u >> 16);
}

// global -> LDS direct copy, 16B per lane. LDS dest must be wave-uniform;
// HW writes lane i at ldsbase + i*16.
__device__ __forceinline__ void gload16(const void* g, void* l) {
  __builtin_amdgcn_global_load_lds(
      (const __attribute__((address_space(1))) void*)g,
      (__attribute__((address_space(3))) void*)l,
      16, 0, 0);
}

// ---------------- fp32 -> bf16 conversion ----------------
__global__ __launch_bounds__(256) void cvt_one(const float* __restrict__ s,
                                               unsigned short* __restrict__ d) {
  const int i = ((int)blockIdx.x * 256 + (int)threadIdx.x) * 8;
  const float4* p = reinterpret_cast<const float4*>(s + i);
  float4 x = p[0], y = p[1];
  ushort8 r;
  r[0] = f2bf(x.x); r[1] = f2bf(x.y); r[2] = f2bf(x.z); r[3] = f2bf(x.w);
  r[4] = f2bf(y.x); r[5] = f2bf(y.y); r[6] = f2bf(y.z); r[7] = f2bf(y.w);
  *reinterpret_cast<ushort8*>(d + i) = r;
}

struct CvtW {
  const float* src[4];
  unsigned short* dst[4];
};
__global__ __launch_bounds__(256) void cvt_w(CvtW a) {
  const int b = blockIdx.x, seg = b >> 9, boff = b & 511;
  const float* s = a.src[seg];
  unsigned short* d = a.dst[seg];
  const int i = (boff * 256 + (int)threadIdx.x) * 8;
  const float4* p = reinterpret_cast<const float4*>(s + i);
  float4 x = p[0], y = p[1];
  ushort8 r;
  r[0] = f2bf(x.x); r[1] = f2bf(x.y); r[2] = f2bf(x.z); r[3] = f2bf(x.w);
  r[4] = f2bf(y.x); r[5] = f2bf(y.y); r[6] = f2bf(y.z); r[7] = f2bf(y.w);
  *reinterpret_cast<ushort8*>(d + i) = r;
}

// ---------------- GEMM: C[M,N] = A[M,K] * Bt[N,K]^T + bias ----------------
// R10 arithmetic: ~55us each ~= 310 TF at 2 blocks/CU -- the 2-barrier loop's
// stage drain is unhidden at this occupancy. T3-minimum restructure: LDS
// double-buffer, stage(t+1) issued BEFORE compute(t), ONE barrier per iter
// (its implicit vmcnt(0) lands after ~200cy of MFMA+ds_read cover).
__global__ __launch_bounds__(256) void gemm_bt(const unsigned short* __restrict__ A,
                                               const unsigned short* __restrict__ Bt,
                                               const float* __restrict__ bias,
                                               void* __restrict__ Cout,
                                               int M, int N, int K, int out_f32) {
  __shared__ alignas(16) unsigned short As[2][128 * 32];  // 8KB per buf
  __shared__ alignas(16) unsigned short Bs[2][128 * 32];
  const int lid = blockIdx.x;                 // 512 blocks
  const int swz = (lid & 7) * 64 + (lid >> 3);
  const int bx = swz >> 3, by = swz & 7;      // 64 row-tiles x 8 col-tiles
  const int tid = threadIdx.x;
  const int wid = tid >> 6, lane = tid & 63;
  const int lg = lane >> 4, li = lane & 15;
  const int row0 = bx * 128, col0 = by * 128;
  const int wr = (wid >> 1) * 64, wc = (wid & 1) * 64;

  f32x4 acc[4][4] = {};

  // staging: 512 chunks of 16B per tile; thread t owns chunks {t, t+256}.
  const int c1 = tid, c2 = tid + 256;
  const size_t aoff1 = (size_t)(row0 + (c1 >> 2)) * K + ((c1 & 3) * 8);
  const size_t aoff2 = (size_t)(row0 + (c2 >> 2)) * K + ((c2 & 3) * 8);
  const size_t boff1 = (size_t)(col0 + (c1 >> 2)) * K + ((c1 & 3) * 8);
  const size_t boff2 = (size_t)(col0 + (c2 >> 2)) * K + ((c2 & 3) * 8);
  char* asb = (char*)As; char* bsb = (char*)Bs;
  char* a_dst1 = asb + wid * 1024;            // + buf*8192
  char* a_dst2 = asb + 4096 + wid * 1024;
  char* b_dst1 = bsb + wid * 1024;
  char* b_dst2 = bsb + 4096 + wid * 1024;

  // prologue: stage tile 0 into buf 0
  gload16(A + aoff1, a_dst1);
  gload16(A + aoff2, a_dst2);
  gload16(Bt + boff1, b_dst1);
  gload16(Bt + boff2, b_dst2);
  __syncthreads();
  int cur = 0;

  for (int k0 = 0; k0 < K; k0 += 32) {
    // issue next-tile stage into buf^1 (overlaps with compute below)
    if (k0 + 32 < K) {
      const int nb = (cur ^ 1) * 8192;
      gload16(A + aoff1 + k0 + 32, a_dst1 + nb);
      gload16(A + aoff2 + k0 + 32, a_dst2 + nb);
      gload16(Bt + boff1 + k0 + 32, b_dst1 + nb);
      gload16(Bt + boff2 + k0 + 32, b_dst2 + nb);
    }
    const unsigned short* Ab = As[cur];
    const unsigned short* Bb = Bs[cur];
    bf16x8 af[4], bfr[4];
#pragma unroll
    for (int i = 0; i < 4; i++) {
      af[i]  = *reinterpret_cast<const bf16x8*>(&Ab[(wr + i * 16 + li) * 32 + lg * 8]);
      bfr[i] = *reinterpret_cast<const bf16x8*>(&Bb[(wc + i * 16 + li) * 32 + lg * 8]);
    }
#pragma unroll
    for (int mi = 0; mi < 4; mi++)
#pragma unroll
      for (int ni = 0; ni < 4; ni++)
        acc[mi][ni] = __builtin_amdgcn_mfma_f32_16x16x32_bf16(af[mi], bfr[ni], acc[mi][ni], 0, 0, 0);
    __syncthreads();   // one barrier/iter: drains stage (vmcnt0) + read-done
    cur ^= 1;
  }

  // epilogue: C/D layout col = li, row = lg*4 + j  [m89-verified]
#pragma unroll
  for (int ni = 0; ni < 4; ni++) {
    const int col = col0 + wc + ni * 16 + li;
    const float bv = bias[col];
#pragma unroll
    for (int mi = 0; mi < 4; mi++) {
#pragma unroll
      for (int j = 0; j < 4; j++) {
        const int row = row0 + wr + mi * 16 + lg * 4 + j;
        const float val = acc[mi][ni][j] + bv;
        if (out_f32) ((float*)Cout)[(size_t)row * N + col] = val;
        else ((unsigned short*)Cout)[(size_t)row * N + col] = f2bf(val);
      }
    }
  }
}

// ---------------- flash attention ----------------
// R10: VALUBusy 50 / MfmaUtil 11 -> VALU+serial-chain bound. This round:
// defer-max (THR=8 nats, skips alpha-exp + wave-skips rescale) and paired
// v_cvt_pk_bf16_f32 for the P->bf16 stores. Structure otherwise identical
// to the R10-validated kernel (K LDS dbuf w/ XOR swizzle, padded Vt/Pb).
__global__ __launch_bounds__(256) void attn(const unsigned short* __restrict__ Qp,
                                            const unsigned short* __restrict__ Kp,
                                            const unsigned short* __restrict__ Vp,
                                            unsigned short* __restrict__ Oc) {
  const int lid = blockIdx.x;                   // 2048 blocks
  const int swz = (lid & 7) * 256 + (lid >> 3);
  const int bh = swz >> 5;                      // 64 (b,h) pairs
  const int b = bh >> 4, h = bh & 15;
  const int q0 = (swz & 31) * 64;
  const int tid = threadIdx.x;
  const int wid = tid >> 6, lane = tid & 63;
  const int lg = lane >> 4, li = lane & 15;

  __shared__ alignas(16) unsigned short Ks[2][64 * 64];  // K dbuf, 8KB each
  __shared__ alignas(16) unsigned short Vt[64][72];      // [dk][key], padded
  __shared__ alignas(16) unsigned short Pb[4][16][72];   // per-wave P tile

  const size_t base = ((size_t)b * SS) * DD + h * DKH;
  const unsigned short* Qb = Qp + base;
  const unsigned short* Kb = Kp + base;
  const unsigned short* Vb = Vp + base;

  const int qrow = q0 + wid * 16 + li;
  const bf16x8 qf0 = *reinterpret_cast<const bf16x8*>(Qb + (size_t)qrow * DD + lg * 8);
  const bf16x8 qf1 = *reinterpret_cast<const bf16x8*>(Qb + (size_t)qrow * DD + 32 + lg * 8);

  f32x4 acc[4] = {};                                  // rows lg*4+j, col li
  float mrow[4] = {-1e30f, -1e30f, -1e30f, -1e30f};
  float lrow[4] = {0.f, 0.f, 0.f, 0.f};

  const int vkey = tid & 63, vdk = (tid >> 6) * 16;   // V staging mapping

  // K staging: 512 chunks of 16B; thread t owns {t, t+256}. Linear LDS dest;
  // source pre-swizzled by (slot ^ row&7) so swizzled ds_read is involutive.
  const int c0 = tid, c1 = tid + 256;
  const int r0c = c0 >> 3, r1c = c1 >> 3;
  const size_t koff0 = (size_t)r0c * DD + (((c0 & 7) ^ (r0c & 7)) * 8);
  const size_t koff1 = (size_t)r1c * DD + (((c1 & 7) ^ (r1c & 7)) * 8);
  char* ksb = (char*)Ks;
  char* kdst0 = ksb + wid * 1024;          // + buf*8192
  char* kdst1 = ksb + 4096 + wid * 1024;

  gload16(Kb + koff0, kdst0);
  gload16(Kb + koff1, kdst1);
  __syncthreads();
  int buf = 0;

  const int swk = li & 7;                  // read-side swizzle key (row&7)

  for (int kv0 = 0; kv0 < SS; kv0 += 64) {
    if (kv0 + 64 < SS) {
      const int nb = buf ^ 1;
      gload16(Kb + (size_t)(kv0 + 64) * DD + koff0, kdst0 + nb * 8192);
      gload16(Kb + (size_t)(kv0 + 64) * DD + koff1, kdst1 + nb * 8192);
    }

    // V tile -> regs (32B contiguous per thread)
    ushort8 v0 = *reinterpret_cast<const ushort8*>(Vb + (size_t)(kv0 + vkey) * DD + vdk);
    ushort8 v1 = *reinterpret_cast<const ushort8*>(Vb + (size_t)(kv0 + vkey) * DD + vdk + 8);

    // QK^T from LDS (swizzled reads: 2 lanes/slot = conflict-free)
    f32x4 sc[4];
#pragma unroll
    for (int n = 0; n < 4; n++) {
      const unsigned short* krow = &Ks[buf][(n * 16 + li) * 64];
      bf16x8 kb0 = *reinterpret_cast<const bf16x8*>(&krow[(lg ^ swk) * 8]);
      bf16x8 kb1 = *reinterpret_cast<const bf16x8*>(&krow[((lg + 4) ^ swk) * 8]);
      f32x4 c = {};
      c = __builtin_amdgcn_mfma_f32_16x16x32_bf16(qf0, kb0, c, 0, 0, 0);
      c = __builtin_amdgcn_mfma_f32_16x16x32_bf16(qf1, kb1, c, 0, 0, 0);
      sc[n] = c;
    }

    // online softmax with defer-max (THR=8): keep old max unless it grows
    // by >8; P values then bounded by e^8 (bf16/f32-safe), normalization
    // by lrow at the end is invariant to the shared m.
    float pvv[4][4]; float alf[4];
    int growAny = 0;
#pragma unroll
    for (int j = 0; j < 4; j++) {
      float mx = fmaxf(fmaxf(sc[0][j], sc[1][j]), fmaxf(sc[2][j], sc[3][j]));
      mx = fmaxf(mx, __shfl_xor(mx, 1, 16));
      mx = fmaxf(mx, __shfl_xor(mx, 2, 16));
      mx = fmaxf(mx, __shfl_xor(mx, 4, 16));
      mx = fmaxf(mx, __shfl_xor(mx, 8, 16));
      mx *= 0.125f;                                   // 1/sqrt(DK)
      float a = 1.0f;
      if (mx > mrow[j] + 8.0f) {                      // rare after iter 0
        a = __expf(mrow[j] - mx);                     // iter 0: exp(-inf)=0
        mrow[j] = mx;
        growAny = 1;
      }
      alf[j] = a;
      float ps = 0.f;
#pragma unroll
      for (int n = 0; n < 4; n++) {
        const float p = __expf(sc[n][j] * 0.125f - mrow[j]);
        pvv[n][j] = p; ps += p;
      }
      ps += __shfl_xor(ps, 1, 16);
      ps += __shfl_xor(ps, 2, 16);
      ps += __shfl_xor(ps, 4, 16);
      ps += __shfl_xor(ps, 8, 16);
      lrow[j] = lrow[j] * a + ps;
    }

    __syncthreads();   // prev-iter Vt/Pb reads done; drains K-stage + V loads
#pragma unroll
    for (int i = 0; i < 8; i++) {          // transposed V store
      Vt[vdk + i][vkey] = v0[i];
      Vt[vdk + 8 + i][vkey] = v1[i];
    }
    // P -> bf16 via paired v_cvt_pk_bf16_f32 (lo = src0, hi = src1)
#pragma unroll
    for (int j = 0; j < 4; j++) {
      unsigned int r01, r23;
      asm("v_cvt_pk_bf16_f32 %0, %1, %2" : "=v"(r01) : "v"(pvv[0][j]), "v"(pvv[1][j]));
      asm("v_cvt_pk_bf16_f32 %0, %1, %2" : "=v"(r23) : "v"(pvv[2][j]), "v"(pvv[3][j]));
      unsigned short* pr = &Pb[wid][lg * 4 + j][li];
      pr[0]  = (unsigned short)(r01 & 0xffffu);
      pr[16] = (unsigned short)(r01 >> 16);
      pr[32] = (unsigned short)(r23 & 0xffffu);
      pr[48] = (unsigned short)(r23 >> 16);
    }
    if (__any(growAny)) {                  // wave-skips in steady state
#pragma unroll
      for (int n = 0; n < 4; n++)
#pragma unroll
        for (int j = 0; j < 4; j++)
          acc[n][j] *= alf[j];
    }
    __syncthreads();   // Vt + P visible

    // PV: A-frag = P rows (m=li), B-frag = Vt rows (n=dk)
    const bf16x8 pf0 = *reinterpret_cast<const bf16x8*>(&Pb[wid][li][lg * 8]);
    const bf16x8 pf1 = *reinterpret_cast<const bf16x8*>(&Pb[wid][li][32 + lg * 8]);
#pragma unroll
    for (int n = 0; n < 4; n++) {
      bf16x8 vb0 = *reinterpret_cast<const bf16x8*>(&Vt[n * 16 + li][lg * 8]);
      bf16x8 vb1 = *reinterpret_cast<const bf16x8*>(&Vt[n * 16 + li][32 + lg * 8]);
      acc[n] = __builtin_amdgcn_mfma_f32_16x16x32_bf16(pf0, vb0, acc[n], 0, 0, 0);
      acc[n] = __builtin_amdgcn_mfma_f32_16x16x32_bf16(pf1, vb1, acc[n], 0, 0, 0);
    }
    buf ^= 1;
  }

  // normalize + store concat (bf16)
  float inv[4];
#pragma unroll
  for (int j = 0; j < 4; j++) inv[j] = 1.0f / lrow[j];
  unsigned short* Ob = Oc + base;
#pragma unroll
  for (int n = 0; n < 4; n++)
#pragma unroll
    for (int j = 0; j < 4; j++) {
      const int r = q0 + wid * 16 + lg * 4 + j;
      Ob[(size_t)r * DD + n * 16 + li] = f2bf(acc[n][j] * inv[j]);
    }
}

// ---------------- launch ----------------
extern "C" void kernel_launch(void* const* d_in, const int* in_sizes, int n_in,
                              void* d_out, int out_size, void* d_ws, size_t ws_size,
                              hipStream_t stream) {
  const float* q  = (const float*)d_in[0];
  const float* k  = (const float*)d_in[1];
  const float* v  = (const float*)d_in[2];
  const float* Wq = (const float*)d_in[3];
  const float* bq = (const float*)d_in[4];
  const float* Wk = (const float*)d_in[5];
  const float* bk = (const float*)d_in[6];
  const float* Wv = (const float*)d_in[7];
  const float* bv = (const float*)d_in[8];
  const float* Wo = (const float*)d_in[9];
  const float* bo = (const float*)d_in[10];
  float* out = (float*)d_out;

  const size_t NE = (size_t)BB * SS * DD;  // 8,388,608
  const size_t WE = (size_t)DD * DD;       // 1,048,576
  unsigned short* ws  = (unsigned short*)d_ws;
  unsigned short* ab  = ws;                // activation staging / attn concat
  unsigned short* Qp  = ab + NE;
  unsigned short* Kp  = Qp + NE;
  unsigned short* Vp  = Kp + NE;
  unsigned short* Wqb = Vp + NE;
  unsigned short* Wkb = Wqb + WE;
  unsigned short* Wvb = Wkb + WE;
  unsigned short* Wob = Wvb + WE;
  (void)ws_size; (void)in_sizes; (void)n_in; (void)out_size;

  CvtW cw;
  cw.src[0] = Wq; cw.dst[0] = Wqb;
  cw.src[1] = Wk; cw.dst[1] = Wkb;
  cw.src[2] = Wv; cw.dst[2] = Wvb;
  cw.src[3] = Wo; cw.dst[3] = Wob;
  cvt_w<<<2048, 256, 0, stream>>>(cw);

  cvt_one<<<4096, 256, 0, stream>>>(q, ab);
  gemm_bt<<<512, 256, 0, stream>>>(ab, Wqb, bq, Qp, 8192, 1024, 1024, 0);
  cvt_one<<<4096, 256, 0, stream>>>(k, ab);
  gemm_bt<<<512, 256, 0, stream>>>(ab, Wkb, bk, Kp, 8192, 1024, 1024, 0);
  cvt_one<<<4096, 256, 0, stream>>>(v, ab);
  gemm_bt<<<512, 256, 0, stream>>>(ab, Wvb, bv, Vp, 8192, 1024, 1024, 0);

  attn<<<2048, 256, 0, stream>>>(Qp, Kp, Vp, ab);   // ab dead -> attn concat

  gemm_bt<<<512, 256, 0, stream>>>(ab, Wob, bo, out, 8192, 1024, 1024, 1);
}